// Round 2
// baseline (102.460 us; speedup 1.0000x reference)
//
#include <hip/hip_runtime.h>

// GAT layer, B=4, N=256, IN=128, H=4, D=64 — fully fused single kernel.
// Index algebra of the reference's tile/view construction (verified R0):
//   e[b,hp,i,j] = lrelu_0.2( f1flat[b*1024 + hp*256 + i] + f2flat[b*1024 + (i&3)*256 + j] )
//   f1[b,n,h] = sum_d a[d]    * Wh[b,n,h,d]   (flat layout b*1024 + n*4 + h)
//   f2[b,n,h] = sum_d a[64+d] * Wh[b,n,h,d]
//   att = softmax_j(adj==0 -> -inf), out[b,i,hp*64+d] = sum_j att*Wh[b,j,hp*64+d]
//
// grid = 256 blocks x 256 threads: <= #CUs and tiny resources => all blocks
// co-resident => software global barrier is safe (agent-scope release/acquire
// handles cross-XCD L2 writeback/invalidate).

#define NBLK 256

__global__ __launch_bounds__(256) void gat_fused(
    const float* __restrict__ h, const float* __restrict__ W,
    const float* __restrict__ a, const int* __restrict__ adj,
    float* __restrict__ Wh, float* __restrict__ f1, float* __restrict__ f2,
    int* __restrict__ bar, float* __restrict__ out)
{
  const int tid  = threadIdx.x;
  const int lane = tid & 63;
  const int wv   = tid >> 6;     // wave id 0..3
  const int blk  = blockIdx.x;

  __shared__ float shA[4][128];       // h rows (phase A)
  __shared__ float att[16][256];      // unnormalized softmax rows (phase B)
  __shared__ float red[16][4][64];    // seg-partials (phase B)
  __shared__ float sinv[16];

  // ================= Phase A: rows r0..r0+3 of Wh = h @ W, plus f1/f2 ========
  const int r0 = blk * 4;            // global row = b*256 + n
  for (int t = tid; t < 512; t += 256) shA[t >> 7][t & 127] = h[r0 * 128 + t];
  __syncthreads();

  const int c = tid;                 // output column 0..255 (head = c>>6, d = c&63)
  float acc0 = 0.f, acc1 = 0.f, acc2 = 0.f, acc3 = 0.f;
  for (int k = 0; k < 128; k++) {
    float w = W[k * 256 + c];
    acc0 += shA[0][k] * w;
    acc1 += shA[1][k] * w;
    acc2 += shA[2][k] * w;
    acc3 += shA[3][k] * w;
  }

  const int d = lane;
  const float a1v = a[d], a2v = a[64 + d];
  float accs[4] = {acc0, acc1, acc2, acc3};
#pragma unroll
  for (int r = 0; r < 4; r++) {
    Wh[(r0 + r) * 256 + c] = accs[r];
    float p1 = a1v * accs[r];
    float p2 = a2v * accs[r];
#pragma unroll
    for (int off = 32; off > 0; off >>= 1) {
      p1 += __shfl_xor(p1, off, 64);
      p2 += __shfl_xor(p2, off, 64);
    }
    if (d == 0) { f1[(r0 + r) * 4 + wv] = p1; f2[(r0 + r) * 4 + wv] = p2; }
  }

  // ================= Global barrier =========================================
  __threadfence();                    // drain this thread's stores to L2
  __syncthreads();                    // all block stores drained
  if (tid == 0) {
    // release @ agent scope: writes back dirty L2 before the atomic
    __hip_atomic_fetch_add(bar, 1, __ATOMIC_RELEASE, __HIP_MEMORY_SCOPE_AGENT);
    int spins = 0;
    while (__hip_atomic_load(bar, __ATOMIC_ACQUIRE, __HIP_MEMORY_SCOPE_AGENT) < NBLK
           && ++spins < (1 << 24)) {}
  }
  __syncthreads();

  // ================= Phase B: one (b, hp, 16-row) attention tile ============
  const int b  = blk >> 6;
  const int hp = (blk >> 4) & 3;
  const int i0 = (blk & 15) * 16;

  // ---- masked softmax: wave wv builds rows rr = wv*4 + rq ----
#pragma unroll
  for (int rq = 0; rq < 4; rq++) {
    const int rr = wv * 4 + rq;
    const int i  = i0 + rr;
    const float s1 = f1[b * 1024 + hp * 256 + i];
    const float* f2row = f2 + b * 1024 + (i & 3) * 256;
    const int* adjrow = adj + (b * 256 + i) * 256;

    float e[4];
    float m = -1e30f;
#pragma unroll
    for (int jq = 0; jq < 4; jq++) {
      int j = lane + jq * 64;
      float ev = s1 + f2row[j];
      ev = ev > 0.f ? ev : 0.2f * ev;           // leaky relu 0.2
      ev = adjrow[j] ? ev : -1e30f;             // mask adj==0
      e[jq] = ev;
      m = fmaxf(m, ev);
    }
#pragma unroll
    for (int off = 32; off > 0; off >>= 1) m = fmaxf(m, __shfl_xor(m, off, 64));

    float s = 0.f;
#pragma unroll
    for (int jq = 0; jq < 4; jq++) {
      float ex = __expf(e[jq] - m);
      s += ex;
      att[rr][lane + jq * 64] = ex;
    }
#pragma unroll
    for (int off = 32; off > 0; off >>= 1) s += __shfl_xor(s, off, 64);
    if (lane == 0) sinv[rr] = 1.f / s;
  }
  __syncthreads();

  // ---- aggregation: out(16r x 64d) = att(16 x 256) @ WhSlice(256 x 64) ----
  // thread: d = lane, seg = wv handles j in [seg*64, seg*64+64), 4 j at a time
  const int seg = wv;
  const float* whp = Wh + b * 65536 + hp * 64 + d;   // j-stride 256 floats
  float acc[16];
#pragma unroll
  for (int r = 0; r < 16; r++) acc[r] = 0.f;

  for (int j4 = 0; j4 < 16; j4++) {
    const int j = seg * 64 + j4 * 4;
    float w0 = whp[(j + 0) * 256];
    float w1 = whp[(j + 1) * 256];
    float w2 = whp[(j + 2) * 256];
    float w3 = whp[(j + 3) * 256];
#pragma unroll
    for (int r = 0; r < 16; r++) {
      float4 a4 = *(const float4*)&att[r][j];    // ds_read_b128 broadcast
      acc[r] += a4.x * w0 + a4.y * w1 + a4.z * w2 + a4.w * w3;
    }
  }
#pragma unroll
  for (int r = 0; r < 16; r++) red[r][seg][d] = acc[r];
  __syncthreads();

#pragma unroll
  for (int rq = 0; rq < 4; rq++) {
    const int r = wv * 4 + rq;
    float o = (red[r][0][d] + red[r][1][d]) + (red[r][2][d] + red[r][3][d]);
    o *= sinv[r];
    out[(b * 256 + i0 + r) * 256 + hp * 64 + d] = o;
  }
}

extern "C" void kernel_launch(void* const* d_in, const int* in_sizes, int n_in,
                              void* d_out, int out_size, void* d_ws, size_t ws_size,
                              hipStream_t stream) {
  const float* h   = (const float*)d_in[0];   // [4,256,128]
  const int*   adj = (const int*)d_in[1];     // [4,256,256]
  const float* W   = (const float*)d_in[2];   // [128,256]
  const float* a   = (const float*)d_in[3];   // [128,1]
  float* out = (float*)d_out;                 // [4,256,256]

  float* Wh = (float*)d_ws;                   // 262144 floats
  float* f1 = Wh + 262144;                    // 4096 floats
  float* f2 = f1 + 4096;                      // 4096 floats
  int*   bar = (int*)(f2 + 4096);             // 1 int barrier counter

  hipMemsetAsync(bar, 0, sizeof(int), stream);
  gat_fused<<<NBLK, 256, 0, stream>>>(h, W, a, adj, Wh, f1, f2, bar, out);
}

// Round 3
// 76.764 us; speedup vs baseline: 1.3347x; 1.3347x over previous
//
#include <hip/hip_runtime.h>

// GAT layer, B=4, N=256, IN=128, H=4, D=64 — two kernels, no global barrier
// (R1 post-mortem: single-counter cross-XCD spin barrier costs ~40 us; banned).
//
// Index algebra of the reference's tile/view construction (verified R0):
//   e[b,hp,i,j] = lrelu_0.2( f1flat[b*1024 + hp*256 + i] + f2flat[b*1024 + (i&3)*256 + j] )
//   f1[b,n,h] = sum_d a[d]    * Wh[b,n,h,d]   (flat layout b*1024 + n*4 + h)
//   f2[b,n,h] = sum_d a[64+d] * Wh[b,n,h,d]
//   att = softmax_j(adj==0 -> -inf), out[b,i,hp*64+d] = sum_j att*Wh[b,j,hp*64+d]

// ---------------- Kernel A: Wh = h @ W, plus f1/f2 via wave reduction ----------
// grid 256 blocks (4 rows each), 256 threads. Full-chip width.
__global__ __launch_bounds__(256) void gat_wh(
    const float* __restrict__ h, const float* __restrict__ W,
    const float* __restrict__ a,
    float* __restrict__ Wh, float* __restrict__ f1, float* __restrict__ f2) {
  const int row0 = blockIdx.x * 4;   // global row = b*256 + n
  const int c = threadIdx.x;         // output column 0..255 (head = c>>6, d = c&63)

  __shared__ float sh[4][128];
  if (c < 128) ((float4*)sh)[c] = ((const float4*)(h + row0 * 128))[c];
  __syncthreads();

  float acc0 = 0.f, acc1 = 0.f, acc2 = 0.f, acc3 = 0.f;
  for (int k = 0; k < 128; k++) {
    float w = W[k * 256 + c];        // coalesced: lanes c consecutive
    acc0 += sh[0][k] * w;
    acc1 += sh[1][k] * w;
    acc2 += sh[2][k] * w;
    acc3 += sh[3][k] * w;
  }

  const int d = c & 63;
  const int wv = c >> 6;             // wave index == head index
  const float a1v = a[d], a2v = a[64 + d];
  float accs[4] = {acc0, acc1, acc2, acc3};
#pragma unroll
  for (int r = 0; r < 4; r++) {
    Wh[(row0 + r) * 256 + c] = accs[r];
    float p1 = a1v * accs[r];
    float p2 = a2v * accs[r];
#pragma unroll
    for (int off = 32; off > 0; off >>= 1) {
      p1 += __shfl_xor(p1, off, 64);
      p2 += __shfl_xor(p2, off, 64);
    }
    if (d == 0) { f1[(row0 + r) * 4 + wv] = p1; f2[(row0 + r) * 4 + wv] = p2; }
  }
}

// ---------------- Kernel B: logits + masked softmax + att @ Wh -----------------
// grid 1024 = 4b x 4hp x 64 itiles (4 rows), 256 threads.
// Aggregation lane map: rg = lane>>4 (row), dg = lane&15 (d-quad):
//  - att read: ONE ds_read_b128 serves 4 rows (4 distinct addrs, conflict-free
//    with +4 row pad) instead of 4 broadcast b128s  -> 4x less LDS pipe.
//  - Wh read: per-lane float4 -> 256 B coalesced global load per instr.
__global__ __launch_bounds__(256) void gat_attn(
    const float* __restrict__ Wh, const float* __restrict__ f1,
    const float* __restrict__ f2, const int* __restrict__ adj,
    float* __restrict__ out) {
  const int blk = blockIdx.x;
  const int it = blk & 63;
  const int hp = (blk >> 6) & 3;
  const int b  = blk >> 8;
  const int i0 = it * 4;

  const int tid = threadIdx.x;
  const int lane = tid & 63;
  const int wv = tid >> 6;           // wave id: softmax row / j-segment

  __shared__ float att[4][260];      // +4 pad: b128 reads conflict-free
  __shared__ float red[16][64];      // [r*4 + seg][d]
  __shared__ float sinv[4];

  // ---- Phase 1: wave wv builds softmax row i0+wv ----
  const int i = i0 + wv;
  const float s1 = f1[b * 1024 + hp * 256 + i];
  const float* f2row = f2 + b * 1024 + (i & 3) * 256;
  const int* adjrow = adj + (b * 256 + i) * 256;

  float e[4];
  float m = -1e30f;
#pragma unroll
  for (int jq = 0; jq < 4; jq++) {
    int j = lane + jq * 64;
    float ev = s1 + f2row[j];
    ev = ev > 0.f ? ev : 0.2f * ev;            // leaky relu 0.2
    ev = adjrow[j] ? ev : -1e30f;              // mask adj==0
    e[jq] = ev;
    m = fmaxf(m, ev);
  }
#pragma unroll
  for (int off = 32; off > 0; off >>= 1) m = fmaxf(m, __shfl_xor(m, off, 64));

  float s = 0.f;
#pragma unroll
  for (int jq = 0; jq < 4; jq++) {
    float ex = __expf(e[jq] - m);
    s += ex;
    att[wv][lane + jq * 64] = ex;
  }
#pragma unroll
  for (int off = 32; off > 0; off >>= 1) s += __shfl_xor(s, off, 64);
  if (lane == 0) sinv[wv] = 1.f / s;
  __syncthreads();

  // ---- Phase 2: aggregation. Thread = (seg=wv, rg, dg); 16 FMA per j4 ----
  const int dg = lane & 15;
  const int rg = lane >> 4;
  const float4* wh4 = (const float4*)Wh;
  const int base4 = b * 16384 + hp * 16 + dg;   // float4 index of Wh[b, j, hp*64+dg*4]

  float ax = 0.f, ay = 0.f, az = 0.f, aw = 0.f;
  for (int j4 = 0; j4 < 16; j4++) {
    const int j = wv * 64 + j4 * 4;
    float4 av = *(const float4*)&att[rg][j];
    float4 w0 = wh4[base4 + (j + 0) * 64];
    float4 w1 = wh4[base4 + (j + 1) * 64];
    float4 w2 = wh4[base4 + (j + 2) * 64];
    float4 w3 = wh4[base4 + (j + 3) * 64];
    ax += av.x * w0.x + av.y * w1.x + av.z * w2.x + av.w * w3.x;
    ay += av.x * w0.y + av.y * w1.y + av.z * w2.y + av.w * w3.y;
    az += av.x * w0.z + av.y * w1.z + av.z * w2.z + av.w * w3.z;
    aw += av.x * w0.w + av.y * w1.w + av.z * w2.w + av.w * w3.w;
  }
  float4 acc = {ax, ay, az, aw};
  *(float4*)&red[rg * 4 + wv][dg * 4] = acc;
  __syncthreads();

  // ---- Final reduce over segments ----
  const int r = tid >> 6;
  const int d = tid & 63;
  float o = (red[r * 4 + 0][d] + red[r * 4 + 1][d]) +
            (red[r * 4 + 2][d] + red[r * 4 + 3][d]);
  o *= sinv[r];
  out[(b * 256 + i0 + r) * 256 + hp * 64 + d] = o;
}

extern "C" void kernel_launch(void* const* d_in, const int* in_sizes, int n_in,
                              void* d_out, int out_size, void* d_ws, size_t ws_size,
                              hipStream_t stream) {
  const float* h   = (const float*)d_in[0];   // [4,256,128]
  const int*   adj = (const int*)d_in[1];     // [4,256,256]
  const float* W   = (const float*)d_in[2];   // [128,256]
  const float* a   = (const float*)d_in[3];   // [128,1]
  float* out = (float*)d_out;                 // [4,256,256]

  float* Wh = (float*)d_ws;                   // 262144 floats
  float* f1 = Wh + 262144;                    // 4096 floats
  float* f2 = f1 + 4096;                      // 4096 floats

  gat_wh<<<256, 256, 0, stream>>>(h, W, a, Wh, f1, f2);
  gat_attn<<<1024, 256, 0, stream>>>(Wh, f1, f2, adj, out);
}

// Round 4
// 75.990 us; speedup vs baseline: 1.3483x; 1.0102x over previous
//
#include <hip/hip_runtime.h>

// GAT layer, B=4, N=256, IN=128, H=4, D=64 — two kernels (dispatch boundary is
// the only safe global barrier; R1 showed a spin barrier costs ~40 us).
//
// Index algebra of the reference's tile/view construction (verified R0):
//   e[b,hp,i,j] = lrelu_0.2( f1flat[b*1024 + hp*256 + i] + f2flat[b*1024 + (i&3)*256 + j] )
//   f1[b,n,h] = sum_d a[d]    * Wh[b,n,h,d]   (flat layout b*1024 + n*4 + h)
//   f2[b,n,h] = sum_d a[64+d] * Wh[b,n,h,d]
//   att = softmax_j(adj==0 -> -inf), out[b,i,hp*64+d] = sum_j att*Wh[b,j,hp*64+d]

// ---------------- Kernel A: Wh = h @ W, plus f1/f2 via wave reduction ----------
// grid 256 blocks (4 rows each), 256 threads. NO LDS: h rows are block-uniform
// -> compiler emits s_load batches through the scalar/constant cache, VALU does
// pure v_fmac with SGPR operand (R2 version burned ~3K LDS-pipe cyc/wave on
// scalar ds_read_b32 broadcasts).
__global__ __launch_bounds__(256) void gat_wh(
    const float* __restrict__ h, const float* __restrict__ W,
    const float* __restrict__ a,
    float* __restrict__ Wh, float* __restrict__ f1, float* __restrict__ f2) {
  const int row0 = blockIdx.x * 4;   // global row = b*256 + n
  const int c = threadIdx.x;         // output column (head = c>>6, d = c&63)
  const float* __restrict__ hr = h + row0 * 128;   // block-uniform base

  float acc0 = 0.f, acc1 = 0.f, acc2 = 0.f, acc3 = 0.f;
#pragma unroll 16
  for (int k = 0; k < 128; k++) {
    float w = W[k * 256 + c];        // coalesced vector load (L1/L2)
    acc0 += hr[k]       * w;         // uniform -> scalar loads
    acc1 += hr[128 + k] * w;
    acc2 += hr[256 + k] * w;
    acc3 += hr[384 + k] * w;
  }

  const int d = c & 63;
  const int wv = c >> 6;             // wave index == head index
  const float a1v = a[d], a2v = a[64 + d];
  float accs[4] = {acc0, acc1, acc2, acc3};
#pragma unroll
  for (int r = 0; r < 4; r++) {
    Wh[(row0 + r) * 256 + c] = accs[r];
    float p1 = a1v * accs[r];
    float p2 = a2v * accs[r];
#pragma unroll
    for (int off = 32; off > 0; off >>= 1) {
      p1 += __shfl_xor(p1, off, 64);
      p2 += __shfl_xor(p2, off, 64);
    }
    if (d == 0) { f1[(row0 + r) * 4 + wv] = p1; f2[(row0 + r) * 4 + wv] = p2; }
  }
}

// ---------------- Kernel B: logits + masked softmax + att @ Wh -----------------
// grid 512 = 4b x 4hp x 32 itiles (8 rows each), 256 threads, 2 blocks/CU.
// 8 rows/block: each att ds_read_b128 feeds 2 rows of FMA, Wh L2 traffic
// halves vs R2 (64 -> 32 MB).
__global__ __launch_bounds__(256) void gat_attn(
    const float* __restrict__ Wh, const float* __restrict__ f1,
    const float* __restrict__ f2, const int* __restrict__ adj,
    float* __restrict__ out) {
  const int blk = blockIdx.x;
  const int it = blk & 31;
  const int hp = (blk >> 5) & 3;
  const int b  = blk >> 7;
  const int i0 = it * 8;

  const int tid = threadIdx.x;
  const int lane = tid & 63;
  const int wv = tid >> 6;           // wave id: softmax rows / j-segment

  __shared__ float att[8][260];      // +4 pad keeps b128 reads conflict-free
  __shared__ float red[32][64];      // [row*4 + seg][d]
  __shared__ float sinv[8];

  // ---- Phase 1: wave wv builds softmax rows 2wv, 2wv+1 ----
#pragma unroll
  for (int rq = 0; rq < 2; rq++) {
    const int rr = wv * 2 + rq;
    const int i  = i0 + rr;
    const float s1 = f1[b * 1024 + hp * 256 + i];
    const float* f2row = f2 + b * 1024 + (i & 3) * 256;
    const int* adjrow = adj + (b * 256 + i) * 256;

    float e[4];
    float m = -1e30f;
#pragma unroll
    for (int jq = 0; jq < 4; jq++) {
      int j = lane + jq * 64;
      float ev = s1 + f2row[j];
      ev = ev > 0.f ? ev : 0.2f * ev;            // leaky relu 0.2
      ev = adjrow[j] ? ev : -1e30f;              // mask adj==0
      e[jq] = ev;
      m = fmaxf(m, ev);
    }
#pragma unroll
    for (int off = 32; off > 0; off >>= 1) m = fmaxf(m, __shfl_xor(m, off, 64));

    float s = 0.f;
#pragma unroll
    for (int jq = 0; jq < 4; jq++) {
      float ex = __expf(e[jq] - m);
      s += ex;
      att[rr][lane + jq * 64] = ex;
    }
#pragma unroll
    for (int off = 32; off > 0; off >>= 1) s += __shfl_xor(s, off, 64);
    if (lane == 0) sinv[rr] = 1.f / s;
  }
  __syncthreads();

  // ---- Phase 2: thread (seg=wv, rg=lane>>4, dg=lane&15) does rows {rg,rg+4},
  //      j in [seg*64, seg*64+64), d in [dg*4, dg*4+4). 32 FMA per 4 VMEM. ----
  const int dg = lane & 15;
  const int rg = lane >> 4;
  const float4* wh4 = (const float4*)Wh;
  const int base4 = b * 16384 + hp * 16 + dg;   // float4 idx of Wh[b, j, hp*64+dg*4]

  float4 acc0 = {0.f, 0.f, 0.f, 0.f};
  float4 acc1 = {0.f, 0.f, 0.f, 0.f};
  for (int j4 = 0; j4 < 16; j4++) {
    const int j = wv * 64 + j4 * 4;
    float4 av0 = *(const float4*)&att[rg][j];
    float4 av1 = *(const float4*)&att[rg + 4][j];
    float4 w0 = wh4[base4 + (j + 0) * 64];
    float4 w1 = wh4[base4 + (j + 1) * 64];
    float4 w2 = wh4[base4 + (j + 2) * 64];
    float4 w3 = wh4[base4 + (j + 3) * 64];
    acc0.x += av0.x * w0.x + av0.y * w1.x + av0.z * w2.x + av0.w * w3.x;
    acc0.y += av0.x * w0.y + av0.y * w1.y + av0.z * w2.y + av0.w * w3.y;
    acc0.z += av0.x * w0.z + av0.y * w1.z + av0.z * w2.z + av0.w * w3.z;
    acc0.w += av0.x * w0.w + av0.y * w1.w + av0.z * w2.w + av0.w * w3.w;
    acc1.x += av1.x * w0.x + av1.y * w1.x + av1.z * w2.x + av1.w * w3.x;
    acc1.y += av1.x * w0.y + av1.y * w1.y + av1.z * w2.y + av1.w * w3.y;
    acc1.z += av1.x * w0.z + av1.y * w1.z + av1.z * w2.z + av1.w * w3.z;
    acc1.w += av1.x * w0.w + av1.y * w1.w + av1.z * w2.w + av1.w * w3.w;
  }
  *(float4*)&red[rg * 4 + wv][dg * 4] = acc0;
  *(float4*)&red[(rg + 4) * 4 + wv][dg * 4] = acc1;
  __syncthreads();

  // ---- Final reduce over segments: thread does rows tid>>6 and (tid>>6)+4 ----
  const int d = tid & 63;
#pragma unroll
  for (int rq = 0; rq < 2; rq++) {
    const int r = (tid >> 6) + rq * 4;
    float o = (red[r * 4 + 0][d] + red[r * 4 + 1][d]) +
              (red[r * 4 + 2][d] + red[r * 4 + 3][d]);
    o *= sinv[r];
    out[(b * 256 + i0 + r) * 256 + hp * 64 + d] = o;
  }
}

extern "C" void kernel_launch(void* const* d_in, const int* in_sizes, int n_in,
                              void* d_out, int out_size, void* d_ws, size_t ws_size,
                              hipStream_t stream) {
  const float* h   = (const float*)d_in[0];   // [4,256,128]
  const int*   adj = (const int*)d_in[1];     // [4,256,256]
  const float* W   = (const float*)d_in[2];   // [128,256]
  const float* a   = (const float*)d_in[3];   // [128,1]
  float* out = (float*)d_out;                 // [4,256,256]

  float* Wh = (float*)d_ws;                   // 262144 floats
  float* f1 = Wh + 262144;                    // 4096 floats
  float* f2 = f1 + 4096;                      // 4096 floats

  gat_wh<<<256, 256, 0, stream>>>(h, W, a, Wh, f1, f2);
  gat_attn<<<512, 256, 0, stream>>>(Wh, f1, f2, adj, out);
}